// Round 3
// baseline (147.144 us; speedup 1.0000x reference)
//
#include <hip/hip_runtime.h>
#include <hip/hip_cooperative_groups.h>

namespace cg = cooperative_groups;

#define B_     8
#define L_     512
#define DIM_   256
#define INNER_ 512
#define M_ROWS (B_*L_)        // 4096

typedef __bf16 bf16x8 __attribute__((ext_vector_type(8)));
typedef float  fl4    __attribute__((ext_vector_type(4)));

typedef const __attribute__((address_space(1))) void gvoid;
typedef __attribute__((address_space(3))) void lvoid;

__device__ __forceinline__ void gl_lds16(const void* g, void* l) {
    __builtin_amdgcn_global_load_lds((gvoid*)g, (lvoid*)l, 16, 0, 0);
}
__device__ __forceinline__ unsigned short f2bf(float f) {
    unsigned int u = __float_as_uint(f);
    u = (u + 0x7fffu + ((u >> 16) & 1u)) >> 16;   // RNE
    return (unsigned short)u;
}
__device__ __forceinline__ float bf2f(unsigned short s) {
    return __uint_as_float(((unsigned int)s) << 16);
}

struct Params {
    const float *x, *Win, *convw, *sdecay, *sscale, *Wout, *normw;
    float* out;
    unsigned short *xb, *winb, *woutb, *xp, *yb;
};

__global__ __launch_bounds__(512) void fused_mamba(Params p)
{
    __shared__ __align__(16) char smem[36*1024];
    cg::grid_group grid = cg::this_grid();
    const int tid  = threadIdx.x;
    const int wave = tid >> 6, lane = tid & 63;
    const int blk  = blockIdx.x;

    // ================= P0: f32 -> bf16 conversion ==================
    {
        const int NX4 = M_ROWS*DIM_/4, NW4 = 2*INNER_*DIM_/4, NO4 = DIM_*INNER_/4;
        for (int i4 = blk*512 + tid; i4 < NX4+NW4+NO4; i4 += 256*512) {
            const float* src; unsigned short* dst; int off;
            if (i4 < NX4)          { src = p.x;    dst = p.xb;    off = i4; }
            else if (i4 < NX4+NW4) { src = p.Win;  dst = p.winb;  off = i4-NX4; }
            else                   { src = p.Wout; dst = p.woutb; off = i4-NX4-NW4; }
            float4 v = *(const float4*)&src[(size_t)off*4];
            ushort4 o; o.x=f2bf(v.x); o.y=f2bf(v.y); o.z=f2bf(v.z); o.w=f2bf(v.w);
            *(ushort4*)&dst[(size_t)off*4] = o;
        }
    }
    grid.sync();

    // ================= P1: gemm1  xp = xb @ winb^T (bf16) ==========
    // 256 blocks = 32 x 8 tiles of 128x128. 8 waves -> wave tile 32x64.
    {
        unsigned short* As = (unsigned short*)smem;           // [128][32]
        unsigned short* Bs = (unsigned short*)(smem + 8192);  // [128][32]
        const int bm = blk >> 3, bn = blk & 7;
        const int wr = (wave >> 1) * 32, wc = (wave & 1) * 64;
        fl4 acc[2][4] = {};
        for (int kt = 0; kt < DIM_; kt += 32) {
            __syncthreads();
            {   // 8 A-chunks + 8 B-chunks of 1KB, one of each per wave
                const int r  = wave*16 + (lane >> 2);
                const int ke = (lane & 3) * 8;
                gl_lds16(p.xb   + (size_t)(bm*128 + r)*DIM_ + kt + ke, (char*)As + wave*1024);
                gl_lds16(p.winb + (size_t)(bn*128 + r)*DIM_ + kt + ke, (char*)Bs + wave*1024);
            }
            __syncthreads();
            bf16x8 af[2], bfr[4];
            #pragma unroll
            for (int m = 0; m < 2; ++m)
                af[m] = *(const bf16x8*)&As[(wr + m*16 + (lane & 15))*32 + (lane >> 4)*8];
            #pragma unroll
            for (int n = 0; n < 4; ++n)
                bfr[n] = *(const bf16x8*)&Bs[(wc + n*16 + (lane & 15))*32 + (lane >> 4)*8];
            #pragma unroll
            for (int m = 0; m < 2; ++m)
                #pragma unroll
                for (int n = 0; n < 4; ++n)
                    acc[m][n] = __builtin_amdgcn_mfma_f32_16x16x32_bf16(af[m], bfr[n], acc[m][n], 0, 0, 0);
        }
        #pragma unroll
        for (int m = 0; m < 2; ++m)
            #pragma unroll
            for (int n = 0; n < 4; ++n)
                #pragma unroll
                for (int r = 0; r < 4; ++r) {
                    const int row = bm*128 + wr + m*16 + (lane >> 4)*4 + r;
                    const int col = bn*128 + wc + n*16 + (lane & 15);
                    p.xp[(size_t)row*1024 + col] = f2bf(acc[m][n][r]);
                }
    }
    grid.sync();

    // ================= P2: conv + scan + gate ======================
    // 256 blocks: b = blk>>5, 32 channel-blocks of 16 ch x 32 chunks of 16 steps.
    {
        float* carry = (float*)smem;                          // [32][16]
        const int b    = blk >> 5;
        const int cb   = blk & 31;
        const int c_lo = tid & 15;
        const int j    = tid >> 4;                            // chunk 0..31
        const int c    = cb*16 + c_lo;

        const float draw = 1.0f / (1.0f + __expf(-p.sdecay[c]));
        const float deff = fmaxf(draw, 1e-6f);
        const float ins  = (1.0f - draw) * p.sscale[c];
        const float w0 = p.convw[c*3+0], w1 = p.convw[c*3+1], w2 = p.convw[c*3+2];

        const int t0 = j*16;
        const size_t rowbase = ((size_t)b*L_ + t0)*1024 + c;

        float h1 = 0.f, h2 = 0.f;
        if (t0 >= 1) h1 = bf2f(p.xp[rowbase - 1024]);
        if (t0 >= 2) h2 = bf2f(p.xp[rowbase - 2048]);

        float sloc[16], gr[16];
        float um1 = h1, um2 = h2, s = 0.f;
        #pragma unroll
        for (int i = 0; i < 16; ++i) {
            const float u = bf2f(p.xp[rowbase + (size_t)i*1024]);
            gr[i] = bf2f(p.xp[rowbase + (size_t)i*1024 + 512]);
            const float uc = fmaf(w2, u, fmaf(w1, um1, w0*um2));
            um2 = um1; um1 = u;
            s = fmaf(deff, s, ins*uc);
            sloc[i] = s;
        }
        carry[j*16 + c_lo] = s;
        __syncthreads();
        const float dp16 = __powf(deff, 16.0f);
        float s0 = 0.f;
        for (int i = 0; i < j; ++i) s0 = fmaf(s0, dp16, carry[i*16 + c_lo]);
        float pw = 1.0f;
        #pragma unroll
        for (int i = 0; i < 16; ++i) {
            pw *= deff;
            const float sv   = fmaf(s0, pw, sloc[i]);
            const float gate = 1.0f / (1.0f + __expf(-gr[i]));
            p.yb[((size_t)b*L_ + t0 + i)*INNER_ + c] = f2bf(sv * gate);
        }
    }
    grid.sync();

    // ================= P3: gemm2 + fused RMSNorm ===================
    // 256 blocks x 16 rows; full 256 output cols per block; K=512, BK=64.
    {
        unsigned short* As2 = (unsigned short*)smem;          // [16][64]
        unsigned short* Bs2 = (unsigned short*)(smem + 2048); // [256][64]
        float* ssp = (float*)(smem + 2048 + 32768);           // [16][8]
        const int row0 = blk * 16;
        const int wc   = wave * 32;
        fl4 acc[2] = {};
        for (int kt = 0; kt < INNER_; kt += 64) {
            __syncthreads();
            for (int ch = wave; ch < 34; ch += 8) {
                const int ke = (lane & 7) * 8;
                if (ch < 2)
                    gl_lds16(p.yb    + (size_t)(row0 + ch*8 + (lane >> 3))*INNER_ + kt + ke,
                             (char*)As2 + ch*1024);
                else
                    gl_lds16(p.woutb + (size_t)((ch-2)*8 + (lane >> 3))*INNER_ + kt + ke,
                             (char*)Bs2 + (ch-2)*1024);
            }
            __syncthreads();
            #pragma unroll
            for (int kh = 0; kh < 2; ++kh) {
                bf16x8 a = *(const bf16x8*)&As2[(lane & 15)*64 + kh*32 + (lane >> 4)*8];
                #pragma unroll
                for (int n = 0; n < 2; ++n) {
                    bf16x8 b = *(const bf16x8*)&Bs2[(wc + n*16 + (lane & 15))*64 + kh*32 + (lane >> 4)*8];
                    acc[n] = __builtin_amdgcn_mfma_f32_16x16x32_bf16(a, b, acc[n], 0, 0, 0);
                }
            }
        }
        // RMSNorm across the full row (held by this block)
        float t[4];
        #pragma unroll
        for (int q = 0; q < 4; ++q) {
            float s = 0.f;
            #pragma unroll
            for (int n = 0; n < 2; ++n) { const float v = acc[n][q]; s = fmaf(v, v, s); }
            s += __shfl_xor(s, 1, 64); s += __shfl_xor(s, 2, 64);
            s += __shfl_xor(s, 4, 64); s += __shfl_xor(s, 8, 64);
            t[q] = s;
        }
        if ((lane & 15) == 0) {
            #pragma unroll
            for (int q = 0; q < 4; ++q)
                ssp[((lane >> 4)*4 + q)*8 + wave] = t[q];
        }
        __syncthreads();
        #pragma unroll
        for (int q = 0; q < 4; ++q) {
            const int rl = (lane >> 4)*4 + q;
            float ss = 0.f;
            #pragma unroll
            for (int w = 0; w < 8; ++w) ss += ssp[rl*8 + w];
            const float rf = rsqrtf(ss * (1.0f/DIM_) + 1e-6f);
            #pragma unroll
            for (int n = 0; n < 2; ++n) {
                const int col = wc + n*16 + (lane & 15);
                p.out[(size_t)(row0 + rl)*DIM_ + col] = acc[n][q] * rf * p.normw[col];
            }
        }
    }
}

// ---------------------------------------------------------------- launch
extern "C" void kernel_launch(void* const* d_in, const int* in_sizes, int n_in,
                              void* d_out, int out_size, void* d_ws, size_t ws_size,
                              hipStream_t stream)
{
    char* ws = (char*)d_ws;
    Params hp;
    hp.x      = (const float*)d_in[0];
    hp.Win    = (const float*)d_in[1];
    hp.convw  = (const float*)d_in[2];
    hp.sdecay = (const float*)d_in[3];
    hp.sscale = (const float*)d_in[4];
    hp.Wout   = (const float*)d_in[5];
    hp.normw  = (const float*)d_in[6];
    hp.out    = (float*)d_out;
    hp.xb     = (unsigned short*)(ws);                          // 2 MB
    hp.winb   = (unsigned short*)(ws + (2u<<20));               // 0.5 MB
    hp.woutb  = (unsigned short*)(ws + (2u<<20) + (512u<<10));  // 0.25 MB
    hp.xp     = (unsigned short*)(ws + (3u<<20));               // 8 MB
    hp.yb     = (unsigned short*)(ws + (11u<<20));              // 4 MB

    void* args[] = { &hp };
    hipLaunchCooperativeKernel((void*)fused_mamba, dim3(256), dim3(512), args, 0, stream);
}

// Round 4
// 36.944 us; speedup vs baseline: 3.9829x; 3.9829x over previous
//
#include <hip/hip_runtime.h>

#define B_     8
#define L_     512
#define DIM_   256
#define INNER_ 512
#define M_ROWS (B_*L_)        // 4096

typedef __bf16 bf16x8 __attribute__((ext_vector_type(8)));
typedef float  fl4    __attribute__((ext_vector_type(4)));

typedef const __attribute__((address_space(1))) void gvoid;
typedef __attribute__((address_space(3))) void lvoid;

__device__ __forceinline__ void gl_lds16(const void* g, void* l) {
    __builtin_amdgcn_global_load_lds((gvoid*)g, (lvoid*)l, 16, 0, 0);
}
__device__ __forceinline__ unsigned short f2bf(float f) {
    unsigned int u = __float_as_uint(f);
    u = (u + 0x7fffu + ((u >> 16) & 1u)) >> 16;   // RNE
    return (unsigned short)u;
}
__device__ __forceinline__ ushort4 f4bf4(float4 v) {
    union { __bf16 h[4]; ushort4 u; } r;
    r.h[0] = (__bf16)v.x; r.h[1] = (__bf16)v.y;
    r.h[2] = (__bf16)v.z; r.h[3] = (__bf16)v.w;
    return r.u;
}

// ---------------------------------------------------------------- K0: Wout f32 -> bf16
__global__ __launch_bounds__(256) void conv_wout(const float* __restrict__ wout,
                                                 unsigned short* __restrict__ woutb)
{
    const int i4 = blockIdx.x * blockDim.x + threadIdx.x;   // 32768 float4s
    float4 v = *(const float4*)&wout[(size_t)i4*4];
    *(ushort4*)&woutb[(size_t)i4*4] = f4bf4(v);
}

// ---------------------------------------------------------------- K1: gemm1 + conv + scan + gate
// Block = one batch b x 16 u-channels (cg*16..) + their 16 g-channels.
// GEMM: C[512][32] = x[b][512][256] . Wrows^T, Wrows = Win[cg*16..+15] ++ Win[512+cg*16..+15]
// Then conv(3) + linear scan over l=0..511 entirely in-block, gate, write yb bf16.
__global__ __launch_bounds__(512) void p1_fused(
    const float* __restrict__ x, const float* __restrict__ Win,
    const float* __restrict__ convw, const float* __restrict__ sdecay,
    const float* __restrict__ sscale,
    unsigned short* __restrict__ yb)
{
    constexpr int BK = 64;
    constexpr int LDA = BK + 8;      // 72 bf16, stride 144 B (bank offset 4/row)
    __shared__ __align__(16) char smem[80*1024];
    unsigned short* As = (unsigned short*)smem;            // [512][72] bf16 = 73728 B
    unsigned short* Bs = (unsigned short*)(smem + 73728);  // [32][72]  bf16 = 4608 B
    float* u_lds = (float*)smem;                           // [512][17] f32 = 34816 B
    float* g_lds = (float*)(smem + 34816);                 // [512][17]
    float* carry = (float*)(smem + 69632);                 // [32][16]

    const int tid  = threadIdx.x;
    const int wave = tid >> 6, lane = tid & 63;
    const int b  = blockIdx.x >> 5;
    const int cg = blockIdx.x & 31;

    fl4 acc[4][2] = {};   // wave rows: wave*64 + m*16..; cols: n=0 -> u, n=1 -> g

    const int kc = (tid & 15) * 4;       // col offset (f32 elems) this thread stages
    const int rsub = tid >> 4;           // 0..31

    for (int kt = 0; kt < DIM_; kt += BK) {
        __syncthreads();
        // stage A: 512 rows x 64 k (f32 -> bf16). thread: rows rsub + p*32, cols kc..kc+3
        #pragma unroll
        for (int p = 0; p < 16; ++p) {
            const int l = p*32 + rsub;
            float4 v = *(const float4*)&x[(size_t)(b*L_ + l)*DIM_ + kt + kc];
            *(ushort4*)&As[l*LDA + kc] = f4bf4(v);
        }
        // stage Win rows (32 x 64): thread rsub = Bs row, cols kc
        {
            const int wrow = (rsub < 16) ? (cg*16 + rsub) : (INNER_ + cg*16 + (rsub-16));
            float4 v = *(const float4*)&Win[(size_t)wrow*DIM_ + kt + kc];
            *(ushort4*)&Bs[rsub*LDA + kc] = f4bf4(v);
        }
        __syncthreads();

        #pragma unroll
        for (int kh = 0; kh < 2; ++kh) {
            bf16x8 af[4], bfr[2];
            #pragma unroll
            for (int m = 0; m < 4; ++m)
                af[m] = *(const bf16x8*)&As[(wave*64 + m*16 + (lane & 15))*LDA + kh*32 + (lane >> 4)*8];
            #pragma unroll
            for (int n = 0; n < 2; ++n)
                bfr[n] = *(const bf16x8*)&Bs[(n*16 + (lane & 15))*LDA + kh*32 + (lane >> 4)*8];
            #pragma unroll
            for (int m = 0; m < 4; ++m)
                #pragma unroll
                for (int n = 0; n < 2; ++n)
                    acc[m][n] = __builtin_amdgcn_mfma_f32_16x16x32_bf16(af[m], bfr[n], acc[m][n], 0, 0, 0);
        }
    }

    __syncthreads();          // all frag reads done; reuse LDS for scan
    #pragma unroll
    for (int m = 0; m < 4; ++m)
        #pragma unroll
        for (int r = 0; r < 4; ++r) {
            const int l = wave*64 + m*16 + (lane >> 4)*4 + r;
            const int c2 = lane & 15;
            u_lds[l*17 + c2] = acc[m][0][r];
            g_lds[l*17 + c2] = acc[m][1][r];
        }
    __syncthreads();

    // scan: thread = channel c2 (0..15) x chunk j (0..31) of 16 steps
    {
        const int c2 = tid & 15;
        const int j  = tid >> 4;
        const int c  = cg*16 + c2;                 // global channel

        const float draw = 1.0f / (1.0f + __expf(-sdecay[c]));
        const float deff = fmaxf(draw, 1e-6f);
        const float ins  = (1.0f - draw) * sscale[c];
        const float w0 = convw[c*3+0], w1 = convw[c*3+1], w2 = convw[c*3+2];

        const int l0 = j*16;
        float um1 = (l0 >= 1) ? u_lds[(l0-1)*17 + c2] : 0.f;
        float um2 = (l0 >= 2) ? u_lds[(l0-2)*17 + c2] : 0.f;

        float sloc[16];
        float s = 0.f;
        #pragma unroll
        for (int i = 0; i < 16; ++i) {
            const float u = u_lds[(l0+i)*17 + c2];
            const float uc = fmaf(w2, u, fmaf(w1, um1, w0*um2));
            um2 = um1; um1 = u;
            s = fmaf(deff, s, ins*uc);
            sloc[i] = s;
        }
        carry[j*16 + c2] = s;
        __syncthreads();
        const float dp16 = __powf(deff, 16.0f);
        float s0 = 0.f;
        for (int i = 0; i < j; ++i) s0 = fmaf(s0, dp16, carry[i*16 + c2]);

        float pw = 1.0f;
        #pragma unroll
        for (int i = 0; i < 16; ++i) {
            pw *= deff;
            const float sv   = fmaf(s0, pw, sloc[i]);
            const float gate = 1.0f / (1.0f + __expf(-g_lds[(l0+i)*17 + c2]));
            yb[(size_t)(b*L_ + l0 + i)*INNER_ + c] = f2bf(sv * gate);
        }
    }
}

// ---------------------------------------------------------------- K2: gemm2 + fused RMSNorm
// 256 blocks x 16 rows; full 256 output cols per block; K = 512, BK = 64.
__global__ __launch_bounds__(512) void p3_gemm2(
    const unsigned short* __restrict__ yb,
    const unsigned short* __restrict__ woutb,
    const float* __restrict__ normw,
    float* __restrict__ out)
{
    __shared__ __align__(16) char smem[36*1024];
    unsigned short* As2 = (unsigned short*)smem;          // [16][64]
    unsigned short* Bs2 = (unsigned short*)(smem + 2048); // [256][64]
    float* ssp = (float*)(smem + 2048 + 32768);           // [16][8]
    const int tid  = threadIdx.x;
    const int wave = tid >> 6, lane = tid & 63;
    const int row0 = blockIdx.x * 16;
    const int wc   = wave * 32;
    fl4 acc[2] = {};
    for (int kt = 0; kt < INNER_; kt += 64) {
        __syncthreads();
        for (int ch = wave; ch < 34; ch += 8) {
            const int ke = (lane & 7) * 8;
            if (ch < 2)
                gl_lds16(yb    + (size_t)(row0 + ch*8 + (lane >> 3))*INNER_ + kt + ke,
                         (char*)As2 + ch*1024);
            else
                gl_lds16(woutb + (size_t)((ch-2)*8 + (lane >> 3))*INNER_ + kt + ke,
                         (char*)Bs2 + (ch-2)*1024);
        }
        __syncthreads();
        #pragma unroll
        for (int kh = 0; kh < 2; ++kh) {
            bf16x8 a = *(const bf16x8*)&As2[(lane & 15)*64 + kh*32 + (lane >> 4)*8];
            #pragma unroll
            for (int n = 0; n < 2; ++n) {
                bf16x8 b = *(const bf16x8*)&Bs2[(wc + n*16 + (lane & 15))*64 + kh*32 + (lane >> 4)*8];
                acc[n] = __builtin_amdgcn_mfma_f32_16x16x32_bf16(a, b, acc[n], 0, 0, 0);
            }
        }
    }
    float t[4];
    #pragma unroll
    for (int q = 0; q < 4; ++q) {
        float s = 0.f;
        #pragma unroll
        for (int n = 0; n < 2; ++n) { const float v = acc[n][q]; s = fmaf(v, v, s); }
        s += __shfl_xor(s, 1, 64); s += __shfl_xor(s, 2, 64);
        s += __shfl_xor(s, 4, 64); s += __shfl_xor(s, 8, 64);
        t[q] = s;
    }
    if ((lane & 15) == 0) {
        #pragma unroll
        for (int q = 0; q < 4; ++q)
            ssp[((lane >> 4)*4 + q)*8 + wave] = t[q];
    }
    __syncthreads();
    #pragma unroll
    for (int q = 0; q < 4; ++q) {
        const int rl = (lane >> 4)*4 + q;
        float ss = 0.f;
        #pragma unroll
        for (int w = 0; w < 8; ++w) ss += ssp[rl*8 + w];
        const float rf = rsqrtf(ss * (1.0f/DIM_) + 1e-6f);
        #pragma unroll
        for (int n = 0; n < 2; ++n) {
            const int col = wc + n*16 + (lane & 15);
            out[(size_t)(row0 + rl)*DIM_ + col] = acc[n][q] * rf * normw[col];
        }
    }
}

// ---------------------------------------------------------------- launch
extern "C" void kernel_launch(void* const* d_in, const int* in_sizes, int n_in,
                              void* d_out, int out_size, void* d_ws, size_t ws_size,
                              hipStream_t stream)
{
    const float* x      = (const float*)d_in[0];
    const float* Win    = (const float*)d_in[1];
    const float* convw  = (const float*)d_in[2];
    const float* sdecay = (const float*)d_in[3];
    const float* sscale = (const float*)d_in[4];
    const float* Wout   = (const float*)d_in[5];
    const float* normw  = (const float*)d_in[6];
    float* out = (float*)d_out;

    char* ws = (char*)d_ws;
    unsigned short* woutb = (unsigned short*)(ws);            // 0.25 MB
    unsigned short* yb    = (unsigned short*)(ws + (1u<<20)); // 4 MB

    conv_wout<<<128, 256, 0, stream>>>(Wout, woutb);
    p1_fused<<<256, 512, 0, stream>>>(x, Win, convw, sdecay, sscale, yb);
    p3_gemm2<<<256, 512, 0, stream>>>(yb, woutb, normw, out);
}